// Round 2
// baseline (593.179 us; speedup 1.0000x reference)
//
#include <hip/hip_runtime.h>
#include <stdint.h>

// One WAVE per 32-bit word (4 waves/block, no LDS, no __syncthreads).
// Word layout: 4 byte-rows of 256 floats each (4 float4s x 64 lanes).
// Lane i holds elements [4i, 4i+4) of every byte-row. The one-hot index of a
// row is recovered with 3 ballots (lane-of-nonzero + 2 sub-offset bits) and
// scalar ffs -- the rest of the word math is wave-uniform SALU.

__device__ __forceinline__ uint32_t row_index(float4 v) {
    const bool nx = v.x != 0.0f, ny = v.y != 0.0f, nz = v.z != 0.0f, nw = v.w != 0.0f;
    const unsigned long long m  = __ballot(nx | ny | nz | nw);
    const unsigned long long m0 = __ballot(ny | nw);          // bit0 of sub-offset
    const unsigned long long m1 = __ballot(nz | nw);          // bit1 of sub-offset
    const int src = __ffsll(m) - 1;                           // lane holding the 1
    return ((uint32_t)src << 2) |
           (uint32_t)((m0 >> src) & 1ull) |
           ((uint32_t)((m1 >> src) & 1ull) << 1);
}

__device__ __forceinline__ float4 onehot4(int j, uint32_t oi) {
    float4 r;
    r.x = ((uint32_t)j     == oi) ? 1.0f : 0.0f;
    r.y = ((uint32_t)j + 1 == oi) ? 1.0f : 0.0f;
    r.z = ((uint32_t)j + 2 == oi) ? 1.0f : 0.0f;
    r.w = ((uint32_t)j + 3 == oi) ? 1.0f : 0.0f;
    return r;
}

__global__ __launch_bounds__(256) void vm_kernel(
    const float4* __restrict__ a4,
    const float4* __restrict__ b4,
    float4* __restrict__ o4,
    int n_words)
{
    const int word = (blockIdx.x << 2) | (threadIdx.x >> 6);
    const int lane = threadIdx.x & 63;
    if (word >= n_words) return;

    const long base = (long)word * 256 + lane;   // float4 units; +64 per byte-row

    // Issue all 8 loads up front so they overlap.
    const float4 av0 = a4[base];       const float4 av1 = a4[base + 64];
    const float4 av2 = a4[base + 128]; const float4 av3 = a4[base + 192];
    const float4 bv0 = b4[base];       const float4 bv1 = b4[base + 64];
    const float4 bv2 = b4[base + 128]; const float4 bv3 = b4[base + 192];

    const uint32_t aw = row_index(av0)        | (row_index(av1) << 8) |
                        (row_index(av2) << 16) | (row_index(av3) << 24);
    const uint32_t bw = row_index(bv0)        | (row_index(bv1) << 8) |
                        (row_index(bv2) << 16) | (row_index(bv3) << 24);

    const uint32_t s = aw + bw;   // 4-byte ripple-carry add, final carry dropped
    const uint32_t o = s ^ aw;    // chained per-byte XOR with operand a

    const int j = lane * 4;
    o4[base]       = onehot4(j,  o        & 255u);
    o4[base + 64]  = onehot4(j, (o >> 8)  & 255u);
    o4[base + 128] = onehot4(j, (o >> 16) & 255u);
    o4[base + 192] = onehot4(j, (o >> 24) & 255u);
}

extern "C" void kernel_launch(void* const* d_in, const int* in_sizes, int n_in,
                              void* d_out, int out_size, void* d_ws, size_t ws_size,
                              hipStream_t stream)
{
    const float4* a4 = (const float4*)d_in[0];   // [B,4,256] one-hot
    const float4* b4 = (const float4*)d_in[1];
    float4* o4 = (float4*)d_out;                 // [B,4,256]
    const int n_words = in_sizes[0] / 1024;      // B
    const int n_blocks = (n_words + 3) / 4;      // one wave per word
    vm_kernel<<<n_blocks, 256, 0, stream>>>(a4, b4, o4, n_words);
}